// Round 7
// baseline (208.682 us; speedup 1.0000x reference)
//
#include <hip/hip_runtime.h>

#define NEGINF (-1e30f)

// ---------------- problem constants ----------------
// b=4, c=64, h=w=5, q=75, u=100, N_WAY=5, K_SHOT=5
// M_s = 125 (per way), M_u = 2500, M_q = 25, M_tot = 2625
// ---------------- workspace layout (float units) ----------------
// Footprint end identical to round-5 proven layout (2,778,960 fu).
// bvg/bpg [300][20][25] ALIAS rowv/rowi (dead after kmerge; kc1 runs
// two kernels later). amaxg stays at its round-2/5-proven offset.
constexpr size_t OF_UNL  = 0;                              // [4][2500][64]
constexpr size_t OF_SUP  = OF_UNL  + (size_t)4*2500*64;    // [4][5][125][64]
constexpr size_t OF_SUPT = OF_SUP  + (size_t)4*5*125*64;   // [4][5][64][128]
constexpr size_t OF_QT   = OF_SUPT + (size_t)4*5*64*128;   // [300][28][64]  (qT: mq-major, 3 pad rows)
constexpr size_t OF_ROWV = OF_QT   + (size_t)300*28*64;    // [4][5][8ck][2500] f
constexpr size_t OF_ROWI = OF_ROWV + (size_t)4*5*8*2500;   // [4][5][8ck][2500] i
constexpr size_t OF_CVI  = OF_ROWI + (size_t)4*5*8*2500;   // [4][5][125][20][2]
constexpr size_t OF_CMP  = OF_CVI  + (size_t)4*5*125*20*2; // [4][5][2500] i
constexpr size_t OF_CNT  = OF_CMP  + (size_t)4*5*2500;     // [20] i
constexpr size_t OF_UNEAR= OF_CNT  + 20;                   // [4][2500] i
constexpr size_t OF_SNEAR= OF_UNEAR+ 10000;                // [4][625]  i
constexpr size_t OF_BV   = OF_ROWV;                        // [300][20][25] f (aliases rowv)
constexpr size_t OF_BP   = OF_ROWI;                        // [300][20][25] i (aliases rowi)
constexpr size_t OF_AMX  = OF_SNEAR + 2500 + 2*37500;      // [300][3200] u8 (r5-proven offset)

typedef __attribute__((ext_vector_type(4)))  float f4s;
typedef __attribute__((ext_vector_type(16))) float f16s;

// ============================================================
// Kernel A: L2-normalize all three tensors into ws layouts.
// Query written TRANSPOSED: qT[bq][mq][c]; rows 25..27 zero-padded.
// (verbatim round-5, bench-proven)
// ============================================================
__global__ __launch_bounds__(256) void knorm(
    const float* __restrict__ sup, const float* __restrict__ qry,
    const float* __restrict__ unl,
    float* __restrict__ unl_n, float* __restrict__ sup_n,
    float* __restrict__ supT, float* __restrict__ qt)
{
    int gid = blockIdx.x * 256 + threadIdx.x;
    if (gid >= 320000) {                       // pad-zero qT rows 25..27
        int t = gid - 320000;
        if (t < 14400) {
            int bq = t / 48, r = t % 48;
            int row = 25 + r / 16, ch = r % 16;
            *(float4*)(qt + ((size_t)bq * 28 + row) * 64 + ch * 4) =
                make_float4(0.f, 0.f, 0.f, 0.f);
        }
        return;
    }
    int loc = gid >> 4;
    int sub = gid & 15;

    const float* src;
    float* dst1; int dstr1;
    float* dst2 = nullptr;

    if (loc < 10000) {
        int b = loc / 2500, m = loc % 2500;
        int u = m / 25, hw = m % 25;
        src  = unl + ((size_t)(b*100 + u) * 64) * 25 + hw;
        dst1 = unl_n + (size_t)loc * 64; dstr1 = 1;
    } else if (loc < 12500) {
        int idx = loc - 10000;
        int b = idx / 625, r = idx % 625;
        int w = r / 125,  n = r % 125;
        int shot = n / 25, hw = n % 25;
        src  = sup + ((size_t)(b*25 + w*5 + shot) * 64) * 25 + hw;
        dst1 = sup_n + (size_t)idx * 64; dstr1 = 1;
        dst2 = supT + ((size_t)(b*5 + w) * 64) * 128 + n;
    } else {
        int idx = loc - 12500;
        int bq = idx / 25, mq = idx % 25;
        src  = qry + ((size_t)bq * 64) * 25 + mq;
        dst1 = qt + ((size_t)bq * 28 + mq) * 64; dstr1 = 1;   // qT row
    }

    float v[4]; float ss = 0.f;
    int c0 = sub * 4;
#pragma unroll
    for (int j = 0; j < 4; ++j) { v[j] = src[(size_t)(c0 + j) * 25]; ss += v[j] * v[j]; }
#pragma unroll
    for (int msk = 1; msk < 16; msk <<= 1) ss += __shfl_xor(ss, msk);
    float sc = 1.f / fmaxf(sqrtf(ss), 1e-12f);
#pragma unroll
    for (int j = 0; j < 4; ++j) {
        float o = v[j] * sc;
        dst1[(size_t)(c0 + j) * dstr1] = o;
        if (dst2) dst2[(size_t)(c0 + j) * 128] = o;
    }
}

// ============================================================
// Kernel B: u2s pass. 1600 blocks x 256 threads.
// (verbatim round-5, bench-proven: sup tile via s_load_dwordx16)
// ============================================================
#define KB2(C) { \
    f16s s0, s1; \
    asm volatile("s_load_dwordx16 %0, %[b], %c[o0]\n\t" \
                 "s_load_dwordx16 %1, %[b], %c[o1]\n\t" \
                 "s_waitcnt lgkmcnt(0)" \
                 : "=s"(s0), "=s"(s1) \
                 : [b]"s"(sbp), [o0]"i"((C)*512), [o1]"i"((C)*512+512)); \
    float2 uv = *(const float2*)&uls[ml * 66 + (C)]; \
    acc[0]  = fmaf(uv.x, s0[0],  fmaf(uv.y, s1[0],  acc[0])); \
    acc[1]  = fmaf(uv.x, s0[1],  fmaf(uv.y, s1[1],  acc[1])); \
    acc[2]  = fmaf(uv.x, s0[2],  fmaf(uv.y, s1[2],  acc[2])); \
    acc[3]  = fmaf(uv.x, s0[3],  fmaf(uv.y, s1[3],  acc[3])); \
    acc[4]  = fmaf(uv.x, s0[4],  fmaf(uv.y, s1[4],  acc[4])); \
    acc[5]  = fmaf(uv.x, s0[5],  fmaf(uv.y, s1[5],  acc[5])); \
    acc[6]  = fmaf(uv.x, s0[6],  fmaf(uv.y, s1[6],  acc[6])); \
    acc[7]  = fmaf(uv.x, s0[7],  fmaf(uv.y, s1[7],  acc[7])); \
    acc[8]  = fmaf(uv.x, s0[8],  fmaf(uv.y, s1[8],  acc[8])); \
    acc[9]  = fmaf(uv.x, s0[9],  fmaf(uv.y, s1[9],  acc[9])); \
    acc[10] = fmaf(uv.x, s0[10], fmaf(uv.y, s1[10], acc[10])); \
    acc[11] = fmaf(uv.x, s0[11], fmaf(uv.y, s1[11], acc[11])); \
    acc[12] = fmaf(uv.x, s0[12], fmaf(uv.y, s1[12], acc[12])); \
    acc[13] = fmaf(uv.x, s0[13], fmaf(uv.y, s1[13], acc[13])); \
    acc[14] = fmaf(uv.x, s0[14], fmaf(uv.y, s1[14], acc[14])); \
    acc[15] = fmaf(uv.x, s0[15], fmaf(uv.y, s1[15], acc[15])); }
#define KB8(C) KB2(C) KB2((C)+2) KB2((C)+4) KB2((C)+6)

__global__ __launch_bounds__(256) void kb(
    const float* __restrict__ unl_n, const float* __restrict__ supT,
    float* __restrict__ rowv, int* __restrict__ rowi, float* __restrict__ colvi)
{
    int bid = blockIdx.x;
    int nc = bid & 3;
    int mb = (bid >> 2) % 20;
    int bw = bid / 80;               // b*5+w
    int b  = bw / 5;
    int tid = threadIdx.x;
    int lane = tid & 63, wv = tid >> 6;

    __shared__ float uls[128 * 66];
    __shared__ float sv_[4][32];
    __shared__ int   si_[4][32];

    int m0 = mb * 128;
    int n0 = nc * 32;

    // stage 128 unl rows (zero-fill past 2500); stride 66 -> float2 writes
    for (int i = tid; i < 128 * 16; i += 256) {
        int row = i >> 4, c4 = (i & 15) * 4;
        int m = m0 + row;
        float4 x = make_float4(0.f, 0.f, 0.f, 0.f);
        if (m < 2500) x = *(const float4*)(unl_n + ((size_t)(b * 2500 + m)) * 64 + c4);
        *(float2*)&uls[row * 66 + c4]     = make_float2(x.x, x.y);
        *(float2*)&uls[row * 66 + c4 + 2] = make_float2(x.z, x.w);
    }
    __syncthreads();

    int ml = tid & 127;              // local m
    int m  = m0 + ml;
    int nh = tid >> 7;               // n-half: 0 or 1 (constant within a wave)
    int nbase = nh * 16;
    int nbu = __builtin_amdgcn_readfirstlane(nbase);
    int nn_total = (125 - n0) < 32 ? (125 - n0) : 32;   // 32,32,32,29
    const float* sbp = supT + ((size_t)bw * 64) * 128 + n0 + nbu;  // wave-uniform

    float acc[16];
#pragma unroll
    for (int j = 0; j < 16; ++j) acc[j] = 0.f;

    KB8(0)  KB8(8)  KB8(16) KB8(24)
    KB8(32) KB8(40) KB8(48) KB8(56)

    // row-side running argmax over this thread's 16 n's (ascending, strict >)
    int nnloc = nn_total - nbase;
    nnloc = nnloc < 0 ? 0 : (nnloc > 16 ? 16 : nnloc);
    float rbv = NEGINF; int rbi = 0;
    for (int j = 0; j < nnloc; ++j)
        if (acc[j] > rbv) { rbv = acc[j]; rbi = n0 + nbase + j; }
    if (m < 2500) {
        int ck = nc * 2 + nh;        // chunk 0..7, ascending global n
        rowv[((size_t)bw * 8 + ck) * 2500 + m] = rbv;
        rowi[((size_t)bw * 8 + ck) * 2500 + m] = rbi;
    }

    // col-side: wave max + ballot/ffs min-m tie-break
#pragma unroll
    for (int j = 0; j < 16; ++j) {
        float v = (m < 2500 && (nbase + j) < nn_total) ? acc[j] : NEGINF;
        float vm = v;
#pragma unroll
        for (int s2 = 1; s2 < 64; s2 <<= 1) vm = fmaxf(vm, __shfl_xor(vm, s2));
        unsigned long long msk = __ballot(v == vm);
        int first = __ffsll((unsigned long long)msk) - 1;
        if (lane == 0) { sv_[wv][nbase + j] = vm; si_[wv][nbase + j] = m0 + (wv & 1) * 64 + first; }
    }
    __syncthreads();
    if (tid < nn_total) {
        int w0 = (tid < 16) ? 0 : 2;
        float v = sv_[w0][tid];     int vi = si_[w0][tid];
        float v2 = sv_[w0 + 1][tid]; int i2 = si_[w0 + 1][tid];
        if (v2 > v || (v2 == v && i2 < vi)) { v = v2; vi = i2; }
        float* cv = colvi + ((((size_t)bw) * 125 + (n0 + tid)) * 20 + mb) * 2;
        cv[0] = v; ((int*)cv)[1] = vi;
    }
}

// ============================================================
// Kernel M: merge partials. 196 blocks x 64. (verbatim round-5)
// ============================================================
__global__ __launch_bounds__(64) void kmerge(
    const float* __restrict__ rowv, const int* __restrict__ rowi,
    const float* __restrict__ colvi,
    int* __restrict__ unear, int* __restrict__ snear)
{
    int it = blockIdx.x * 64 + threadIdx.x;
    if (it < 10000) {
        int b = it / 2500, m = it % 2500;
        float bv = NEGINF; int bi = 0;
#pragma unroll
        for (int w = 0; w < 5; ++w) {
#pragma unroll
            for (int ck = 0; ck < 8; ++ck) {
                size_t o = (((size_t)(b * 5 + w)) * 8 + ck) * 2500 + m;
                float v = rowv[o];
                if (v > bv) { bv = v; bi = w * 125 + rowi[o]; }
            }
        }
        unear[it] = bi;
    } else if (it < 12500) {
        int idx = it - 10000;
        const float* p = colvi + (size_t)idx * 40;
        float bv = NEGINF; int bi = 0x7fffffff;
        for (int mb2 = 0; mb2 < 20; ++mb2) {
            float v = p[mb2 * 2]; int vi = ((const int*)p)[mb2 * 2 + 1];
            if (v > bv || (v == bv && vi < bi)) { bv = v; bi = vi; }
        }
        snear[idx] = bi;
    }
}

// ============================================================
// Kernel P: mutual-NN mask + stable stream compaction. 20 blocks x 256.
// (verbatim round-5)
// ============================================================
__global__ __launch_bounds__(256) void kcmp(
    const int* __restrict__ unear, const int* __restrict__ snear,
    int* __restrict__ cmp, int* __restrict__ cntg)
{
    int p = blockIdx.x;
    int b = p / 5, way = p % 5;
    int tid = threadIdx.x, lane = tid & 63, wv = tid >> 6;
    __shared__ unsigned long long masks[40];
    __shared__ int base[40];

    for (int ch = wv; ch < 40; ch += 4) {
        int m = ch * 64 + lane;
        bool ok = false;
        if (m < 2500) {
            int un = unear[b * 2500 + m];
            ok = (un / 125 == way) && (snear[b * 625 + un] == m);
        }
        unsigned long long msk = __ballot(ok ? 1 : 0);
        if (lane == 0) masks[ch] = msk;
    }
    __syncthreads();
    if (tid == 0) {
        int s = 0;
        for (int ch = 0; ch < 40; ++ch) { base[ch] = s; s += __popcll(masks[ch]); }
        cntg[p] = s;
    }
    __syncthreads();
    for (int ch = wv; ch < 40; ch += 4) {
        unsigned long long msk = masks[ch];
        if ((msk >> lane) & 1ull) {
            int pre = __popcll(msk & ((1ull << lane) - 1ull));
            cmp[(size_t)p * 2500 + base[ch] + pre] = ch * 64 + lane;
        }
    }
}

// ============================================================
// Kernel C1, round-14: batch-split of the ROUND-5-PROVEN kc1.
// Grid 6000 = (bq,w,bt<4); one 64-col batch per block. Diagnosis
// (r5 counters): 56% stall = serial lgkmcnt(0) SMEM drains x ~3.5
// waves/SIMD; splitting batches across blocks raises residency and
// cuts the per-block drain chain 3x. ONLY proven parts reused: r5
// QLOAD dwordx4 asm (28 SGPRs), r5 plain-C cntg prologue, r5
// staging/CGSTEP/reduce bodies. The r3 QLOAD8 + scalar-prologue asm
// (the bisected crash suspects) are NOT used. Partials go to
// bvg/bpg[300][20][25] (aliased onto dead rowv/rowi); kce merges by
// (v, min-p): p total-orders (w,n) within a way, so min-p == min-n
// == the original ascending-scan tie-break. Ghost pad folded into
// bt=0's partial. Inactive batches write NEGINF partials.
// ============================================================
#define QLOAD(CG, Q0,Q1,Q2,Q3,Q4,Q5,Q6) \
  asm volatile( \
    "s_load_dwordx4 %0, %[b], %c[o0]\n\t" \
    "s_load_dwordx4 %1, %[b], %c[o1]\n\t" \
    "s_load_dwordx4 %2, %[b], %c[o2]\n\t" \
    "s_load_dwordx4 %3, %[b], %c[o3]\n\t" \
    "s_load_dwordx4 %4, %[b], %c[o4]\n\t" \
    "s_load_dwordx4 %5, %[b], %c[o5]\n\t" \
    "s_load_dwordx4 %6, %[b], %c[o6]\n\t" \
    "s_waitcnt lgkmcnt(0)" \
    : "=s"(Q0), "=s"(Q1), "=s"(Q2), "=s"(Q3), "=s"(Q4), "=s"(Q5), "=s"(Q6) \
    : [b]"s"(qbp), \
      [o0]"i"((CG)*16 + 0*256), [o1]"i"((CG)*16 + 1*256), \
      [o2]"i"((CG)*16 + 2*256), [o3]"i"((CG)*16 + 3*256), \
      [o4]"i"((CG)*16 + 4*256), [o5]"i"((CG)*16 + 5*256), \
      [o6]"i"((CG)*16 + 6*256))

#define CGSTEP(CG) { \
    f4s q0,q1,q2,q3,q4,q5,q6; \
    QLOAD(CG, q0,q1,q2,q3,q4,q5,q6); \
    float4 cl = *(const float4*)&cls[lane * 68 + (CG) * 4]; \
    acc[0]=fmaf(q0.x,cl.x,fmaf(q0.y,cl.y,fmaf(q0.z,cl.z,fmaf(q0.w,cl.w,acc[0])))); \
    acc[1]=fmaf(q1.x,cl.x,fmaf(q1.y,cl.y,fmaf(q1.z,cl.z,fmaf(q1.w,cl.w,acc[1])))); \
    acc[2]=fmaf(q2.x,cl.x,fmaf(q2.y,cl.y,fmaf(q2.z,cl.z,fmaf(q2.w,cl.w,acc[2])))); \
    acc[3]=fmaf(q3.x,cl.x,fmaf(q3.y,cl.y,fmaf(q3.z,cl.z,fmaf(q3.w,cl.w,acc[3])))); \
    acc[4]=fmaf(q4.x,cl.x,fmaf(q4.y,cl.y,fmaf(q4.z,cl.z,fmaf(q4.w,cl.w,acc[4])))); \
    acc[5]=fmaf(q5.x,cl.x,fmaf(q5.y,cl.y,fmaf(q5.z,cl.z,fmaf(q5.w,cl.w,acc[5])))); \
    acc[6]=fmaf(q6.x,cl.x,fmaf(q6.y,cl.y,fmaf(q6.z,cl.z,fmaf(q6.w,cl.w,acc[6])))); }

__global__ __launch_bounds__(256) void kc1(
    const float* __restrict__ qt, const float* __restrict__ sup_n,
    const float* __restrict__ unl_n, const int* __restrict__ cmp,
    const int* __restrict__ cntg,
    float* __restrict__ bvg, int* __restrict__ bpg,
    unsigned char* __restrict__ amaxg)
{
    int bid = blockIdx.x;
    int bt = bid & 3;                 // batch index 0..3
    int w  = (bid >> 2) % 5;
    int bq = bid / 20;
    int b = bq / 75;
    int tid = threadIdx.x;
    int lane = tid & 63;
    int wvu = __builtin_amdgcn_readfirstlane(tid >> 6);   // wave id, SGPR
    int pbw = b * 5 + w;

    // plain-C cntg prologue (verbatim round-5, proven)
    int L = 0;
#pragma unroll
    for (int i = 0; i < 20; ++i) { int v = cntg[i]; L = L > v ? L : v; }
    int cntw = 0, wb = 0;
#pragma unroll
    for (int w2 = 0; w2 < 5; ++w2) {
        int c2 = cntg[b * 5 + w2];
        if (w2 < w) wb += 125 + c2;
        if (w2 == w) cntw = c2;
    }
    int cw = 125 + cntw;             // 125..250

    size_t pb20 = ((size_t)bq * 20 + w * 4 + bt) * 25;
    if (bt * 64 >= cw) {             // inactive batch: empty partials
        if (tid < 25) { bvg[pb20 + tid] = NEGINF; bpg[pb20 + tid] = 0x7fffffff; }
        return;
    }

    __shared__ float cls[64 * 68];   // 64 cols x 64c, stride 68 (16B-aligned rows)
    __shared__ float amxv[4][64];
    __shared__ int   amxg_[4][64];

    // wave-uniform Q base: qT + bq*28*64 + (wvu*7)*64  (rows 25..27 zeroed)
    const float* qbp = qt + ((size_t)bq * 28 + wvu * 7) * 64;

    // stage this batch's 64 cols (zero past cw): coalesced 16-lane rows
#pragma unroll
    for (int k = 0; k < 4; ++k) {
        int i = tid + k * 256;
        int row = i >> 4, ch = i & 15;
        int n = bt * 64 + row;
        float4 x = make_float4(0.f, 0.f, 0.f, 0.f);
        if (n < cw) {
            const float* cp;
            if (n < 125) cp = sup_n + (((size_t)pbw) * 125 + n) * 64;
            else { int m = cmp[((size_t)pbw) * 2500 + (n - 125)];
                   cp = unl_n + ((size_t)(b * 2500 + m)) * 64; }
            x = *(const float4*)(cp + ch * 4);
        }
        *(float4*)&cls[row * 68 + ch * 4] = x;
    }
    __syncthreads();

    float acc[7];
#pragma unroll
    for (int j = 0; j < 7; ++j) acc[j] = 0.f;

    CGSTEP(0);  CGSTEP(1);  CGSTEP(2);  CGSTEP(3);
    CGSTEP(4);  CGSTEP(5);  CGSTEP(6);  CGSTEP(7);
    CGSTEP(8);  CGSTEP(9);  CGSTEP(10); CGSTEP(11);
    CGSTEP(12); CGSTEP(13); CGSTEP(14); CGSTEP(15);

    bool colvalid = (bt * 64 + lane) < cw;
    float cmax = NEGINF; int cam = 0;
#pragma unroll
    for (int j = 0; j < 7; ++j) {
        int mq = wvu * 7 + j;
        float s = (acc[j] + 1.0f) * 0.5f;
        float sm = (colvalid && mq < 25) ? s : NEGINF;
        if (sm > cmax) { cmax = sm; cam = mq; }      // col-argmax partial (min mq)
        float vm = sm;                                // row-argmax over 64 cols
#pragma unroll
        for (int t = 1; t < 64; t <<= 1) vm = fmaxf(vm, __shfl_xor(vm, t));
        unsigned long long msk = __ballot(sm == vm);
        int first = __ffsll(msk) - 1;                 // min lane == min col
        if (lane == 0 && mq < 25) {
            int nn = bt * 64 + first;
            float v = vm;
            int p = ((w * 2625 + nn) << 12) | (wb + nn);
            if (bt == 0 && L > cntw) {                // ghost pad column (0.5)
                int pp = ((w * 2625 + 125 + cntw) << 12) | 0xFFF;
                if (0.5f > v || (0.5f == v && pp < p)) { v = 0.5f; p = pp; }
            }
            bvg[pb20 + mq] = v; bpg[pb20 + mq] = p;
        }
    }
    amxv[wvu][lane] = cmax; amxg_[wvu][lane] = cam;
    __syncthreads();

    if (tid < 64) {
        int n = bt * 64 + tid;
        if (n < cw) {
            float v = amxv[0][tid]; int g = amxg_[0][tid];
#pragma unroll
            for (int g2 = 1; g2 < 4; ++g2)
                if (amxv[g2][tid] > v) { v = amxv[g2][tid]; g = amxg_[g2][tid]; }
            amaxg[(size_t)bq * 3200 + (wb + n)] = (unsigned char)g;
        }
    }
}

// ============================================================
// Kernel CE: merge 20 (way,batch) partials per (bq,mq), mutual mask,
// row loss, atomicAdd into d_out. 300 blocks x 64.
// ============================================================
__global__ __launch_bounds__(64) void kce(
    const float* __restrict__ bvg, const int* __restrict__ bpg,
    const unsigned char* __restrict__ amaxg, const int* __restrict__ qy,
    float* __restrict__ out)
{
    int bq = blockIdx.x;
    int tid = threadIdx.x;
    __shared__ float mg[5][25];
    __shared__ float qmask[25];
    __shared__ float lg[5];
    if (tid < 25) {
        float bestv = NEGINF; int bestp = 0x7fffffff;
#pragma unroll
        for (int w = 0; w < 5; ++w) {
            float vw = NEGINF; int pw = 0x7fffffff;
#pragma unroll
            for (int bt = 0; bt < 4; ++bt) {
                size_t o = ((size_t)bq * 20 + w * 4 + bt) * 25 + tid;
                float v2 = bvg[o]; int p2 = bpg[o];
                if (v2 > vw || (v2 == vw && p2 < pw)) { vw = v2; pw = p2; }
            }
            mg[w][tid] = vw;
            if (vw > bestv || (vw == bestv && pw < bestp)) { bestv = vw; bestp = pw; }
        }
        int pos = bestp & 0xFFF;
        int g = (pos == 0xFFF) ? 0 : (int)amaxg[(size_t)bq * 3200 + pos];
        qmask[tid] = (g == tid) ? 1.0f : 0.0f;
    }
    __syncthreads();
    if (tid < 5) {
        float s = 0.f;
#pragma unroll
        for (int mq = 0; mq < 25; ++mq)
            s += mg[tid][mq] * qmask[mq];
        lg[tid] = s;
    }
    __syncthreads();
    if (tid == 0) {
        int y = qy[bq];
        float mx = lg[0];
#pragma unroll
        for (int w = 1; w < 5; ++w) mx = fmaxf(mx, lg[w]);
        float se = 0.f;
#pragma unroll
        for (int w = 0; w < 5; ++w) se += expf(lg[w] - mx);
        float loss = -(lg[y] - mx - logf(se));
        atomicAdd(out, loss * (1.0f / 300.0f));
    }
}

// ============================================================
extern "C" void kernel_launch(void* const* d_in, const int* in_sizes, int n_in,
                              void* d_out, int out_size, void* d_ws, size_t ws_size,
                              hipStream_t stream)
{
    const float* sup = (const float*)d_in[0];
    const float* qry = (const float*)d_in[2];
    const int*   qy  = (const int*)d_in[3];
    const float* unl = (const float*)d_in[4];

    float* ws    = (float*)d_ws;
    float* unl_n = ws + OF_UNL;
    float* sup_n = ws + OF_SUP;
    float* supT  = ws + OF_SUPT;
    float* qt    = ws + OF_QT;
    float* rowv  = ws + OF_ROWV;
    int*   rowi  = (int*)(ws + OF_ROWI);
    float* colvi = ws + OF_CVI;
    int*   cmp   = (int*)(ws + OF_CMP);
    int*   cntg  = (int*)(ws + OF_CNT);
    int*   unear = (int*)(ws + OF_UNEAR);
    int*   snear = (int*)(ws + OF_SNEAR);
    float* bvg   = ws + OF_BV;
    int*   bpg   = (int*)(ws + OF_BP);
    unsigned char* amaxg = (unsigned char*)(ws + OF_AMX);

    hipMemsetAsync(d_out, 0, sizeof(float), stream);

    hipLaunchKernelGGL(knorm, dim3(1307), dim3(256), 0, stream,
                       sup, qry, unl, unl_n, sup_n, supT, qt);
    hipLaunchKernelGGL(kb, dim3(1600), dim3(256), 0, stream,
                       unl_n, supT, rowv, rowi, colvi);
    hipLaunchKernelGGL(kmerge, dim3(196), dim3(64), 0, stream,
                       rowv, rowi, colvi, unear, snear);
    hipLaunchKernelGGL(kcmp, dim3(20), dim3(256), 0, stream,
                       unear, snear, cmp, cntg);
    hipLaunchKernelGGL(kc1, dim3(6000), dim3(256), 0, stream,
                       qt, sup_n, unl_n, cmp, cntg, bvg, bpg, amaxg);
    hipLaunchKernelGGL(kce, dim3(300), dim3(64), 0, stream,
                       bvg, bpg, amaxg, qy, (float*)d_out);
}

// Round 8
// 180.447 us; speedup vs baseline: 1.1565x; 1.1565x over previous
//
#include <hip/hip_runtime.h>

#define NEGINF (-1e30f)

// ---------------- problem constants ----------------
// b=4, c=64, h=w=5, q=75, u=100, N_WAY=5, K_SHOT=5
// M_s = 125 (per way), M_u = 2500, M_q = 25, M_tot = 2625
// ---------------- workspace layout (float units) ----------------
// Round-5 proven layout.
constexpr size_t OF_UNL  = 0;                              // [4][2500][64]
constexpr size_t OF_SUP  = OF_UNL  + (size_t)4*2500*64;    // [4][5][125][64]
constexpr size_t OF_SUPT = OF_SUP  + (size_t)4*5*125*64;   // [4][5][64][128]
constexpr size_t OF_QT   = OF_SUPT + (size_t)4*5*64*128;   // [300][28][64]  (qT: mq-major, 3 pad rows)
constexpr size_t OF_ROWV = OF_QT   + (size_t)300*28*64;    // [4][5][8ck][2500] f
constexpr size_t OF_ROWI = OF_ROWV + (size_t)4*5*8*2500;   // [4][5][8ck][2500] i
constexpr size_t OF_CVI  = OF_ROWI + (size_t)4*5*8*2500;   // [4][5][125][20][2]
constexpr size_t OF_CMP  = OF_CVI  + (size_t)4*5*125*20*2; // [4][5][2500] i
constexpr size_t OF_CNT  = OF_CMP  + (size_t)4*5*2500;     // [20] i
constexpr size_t OF_UNEAR= OF_CNT  + 20;                   // [4][2500] i
constexpr size_t OF_SNEAR= OF_UNEAR+ 10000;                // [4][625]  i
constexpr size_t OF_BV   = OF_SNEAR+ 2500;                 // [300][5][25] f
constexpr size_t OF_BP   = OF_BV   + 37500;                // [300][5][25] i
constexpr size_t OF_AMX  = OF_BP   + 37500;                // [300][3200] u8

typedef __attribute__((ext_vector_type(4)))  float f4s;
typedef __attribute__((ext_vector_type(16))) float f16s;

// ============================================================
// Kernel A, round-15 rewrite: coalesced LDS-transpose normalize.
// Old knorm: 16 lanes/loc each reading 4 floats at 100B stride
// (uncoalesced), supT scalar stores at 512B stride, qt scattered.
// New: one WAVE per 64cx25hw unit (800 units = 400 unl + 100 sup
// + 300 qry; 200 blocks x 4 waves). Coalesced float4 loads -> LDS
// linear -> per-hw scale -> coalesced float4 transposed stores.
// Reduction order preserved bit-exactly vs old shfl_xor butterfly:
// 16 partials of 4 sequential c-squares, then binary tree.
// supT pad columns 125..127 left untouched (garbage), same as old
// kernel; kb masks them (proven behavior).
// ============================================================
__global__ __launch_bounds__(256) void knorm(
    const float* __restrict__ sup, const float* __restrict__ qry,
    const float* __restrict__ unl,
    float* __restrict__ unl_n, float* __restrict__ sup_n,
    float* __restrict__ supT, float* __restrict__ qt)
{
    int tid = threadIdx.x;
    int lane = tid & 63, wv = tid >> 6;
    int unit = blockIdx.x * 4 + wv;      // 0..799 exactly

    __shared__ float ls[4][1600];
    __shared__ float scl[4][32];

    const float* src;
    float* dstT;                 // transposed output base (1600 contiguous)
    float* dst2 = nullptr;       // supT base (sup units only)
    int dst2_shot = 0;
    bool isq = false;

    if (unit < 400) {
        int b = unit / 100, u = unit % 100;
        src  = unl + (size_t)unit * 1600;                       // (b*100+u)==unit
        dstT = unl_n + ((size_t)(b * 2500 + u * 25)) * 64;
    } else if (unit < 500) {
        int idx2 = unit - 400;
        int b = idx2 / 25, r = idx2 % 25;                       // r = w*5+shot
        int w = r / 5, shot = r % 5;
        src  = sup + (size_t)(b * 25 + r) * 1600;
        dstT = sup_n + ((size_t)(b * 625 + w * 125 + shot * 25)) * 64;
        dst2 = supT + ((size_t)(b * 5 + w) * 64) * 128;
        dst2_shot = shot * 25;
    } else {
        int bq = unit - 500;
        src  = qry + (size_t)bq * 1600;
        dstT = qt + (size_t)bq * 1792;                          // 28*64
        isq = true;
    }

    // coalesced load: 400 float4 per unit -> LDS linear [c*25+hw]
    const float4* s4 = (const float4*)src;
#pragma unroll
    for (int k = 0; k < 7; ++k) {
        int idx = k * 64 + lane;
        if (idx < 400) *(float4*)&ls[wv][idx * 4] = s4[idx];
    }
    __syncthreads();

    // per-hw scale; order == old butterfly: p[sub]=sum of 4 seq squares, tree
    if (lane < 25) {
        int hw = lane;
        float p[16];
#pragma unroll
        for (int sub = 0; sub < 16; ++sub) {
            float s = 0.f;
#pragma unroll
            for (int j = 0; j < 4; ++j) {
                float v = ls[wv][(sub * 4 + j) * 25 + hw];
                s += v * v;
            }
            p[sub] = s;
        }
#pragma unroll
        for (int st = 1; st < 16; st <<= 1)
#pragma unroll
            for (int i = 0; i < 16; i += 2 * st)
                p[i] = p[i] + p[i + st];
        scl[wv][hw] = 1.f / fmaxf(sqrtf(p[0]), 1e-12f);
    }
    __syncthreads();

    // transposed scaled store: out[hw][c], 400 float4 coalesced
    float4* d4 = (float4*)dstT;
#pragma unroll
    for (int k = 0; k < 7; ++k) {
        int idx = k * 64 + lane;
        if (idx < 400) {
            int f = idx * 4;
            int r_ = f >> 6;         // hw row 0..24
            int c0 = f & 63;
            float m = scl[wv][r_];
            float4 o;
            o.x = ls[wv][ c0      * 25 + r_] * m;
            o.y = ls[wv][(c0 + 1) * 25 + r_] * m;
            o.z = ls[wv][(c0 + 2) * 25 + r_] * m;
            o.w = ls[wv][(c0 + 3) * 25 + r_] * m;
            d4[idx] = o;
        }
    }
    if (isq) {                       // zero qT rows 25..27 (48 float4)
        if (lane < 48) d4[400 + lane] = make_float4(0.f, 0.f, 0.f, 0.f);
    }
    if (dst2) {                      // supT[c][shot*25+hw] = scaled value
#pragma unroll
        for (int k = 0; k < 25; ++k) {
            int idx = k * 64 + lane;             // < 1600 always
            int c = idx / 25, hw2 = idx % 25;
            dst2[(size_t)c * 128 + dst2_shot + hw2] = ls[wv][idx] * scl[wv][hw2];
        }
    }
}

// ============================================================
// Kernel B: u2s pass. 1600 blocks x 256 threads.
// (verbatim round-5, bench-proven: sup tile via s_load_dwordx16)
// ============================================================
#define KB2(C) { \
    f16s s0, s1; \
    asm volatile("s_load_dwordx16 %0, %[b], %c[o0]\n\t" \
                 "s_load_dwordx16 %1, %[b], %c[o1]\n\t" \
                 "s_waitcnt lgkmcnt(0)" \
                 : "=s"(s0), "=s"(s1) \
                 : [b]"s"(sbp), [o0]"i"((C)*512), [o1]"i"((C)*512+512)); \
    float2 uv = *(const float2*)&uls[ml * 66 + (C)]; \
    acc[0]  = fmaf(uv.x, s0[0],  fmaf(uv.y, s1[0],  acc[0])); \
    acc[1]  = fmaf(uv.x, s0[1],  fmaf(uv.y, s1[1],  acc[1])); \
    acc[2]  = fmaf(uv.x, s0[2],  fmaf(uv.y, s1[2],  acc[2])); \
    acc[3]  = fmaf(uv.x, s0[3],  fmaf(uv.y, s1[3],  acc[3])); \
    acc[4]  = fmaf(uv.x, s0[4],  fmaf(uv.y, s1[4],  acc[4])); \
    acc[5]  = fmaf(uv.x, s0[5],  fmaf(uv.y, s1[5],  acc[5])); \
    acc[6]  = fmaf(uv.x, s0[6],  fmaf(uv.y, s1[6],  acc[6])); \
    acc[7]  = fmaf(uv.x, s0[7],  fmaf(uv.y, s1[7],  acc[7])); \
    acc[8]  = fmaf(uv.x, s0[8],  fmaf(uv.y, s1[8],  acc[8])); \
    acc[9]  = fmaf(uv.x, s0[9],  fmaf(uv.y, s1[9],  acc[9])); \
    acc[10] = fmaf(uv.x, s0[10], fmaf(uv.y, s1[10], acc[10])); \
    acc[11] = fmaf(uv.x, s0[11], fmaf(uv.y, s1[11], acc[11])); \
    acc[12] = fmaf(uv.x, s0[12], fmaf(uv.y, s1[12], acc[12])); \
    acc[13] = fmaf(uv.x, s0[13], fmaf(uv.y, s1[13], acc[13])); \
    acc[14] = fmaf(uv.x, s0[14], fmaf(uv.y, s1[14], acc[14])); \
    acc[15] = fmaf(uv.x, s0[15], fmaf(uv.y, s1[15], acc[15])); }
#define KB8(C) KB2(C) KB2((C)+2) KB2((C)+4) KB2((C)+6)

__global__ __launch_bounds__(256) void kb(
    const float* __restrict__ unl_n, const float* __restrict__ supT,
    float* __restrict__ rowv, int* __restrict__ rowi, float* __restrict__ colvi)
{
    int bid = blockIdx.x;
    int nc = bid & 3;
    int mb = (bid >> 2) % 20;
    int bw = bid / 80;               // b*5+w
    int b  = bw / 5;
    int tid = threadIdx.x;
    int lane = tid & 63, wv = tid >> 6;

    __shared__ float uls[128 * 66];
    __shared__ float sv_[4][32];
    __shared__ int   si_[4][32];

    int m0 = mb * 128;
    int n0 = nc * 32;

    // stage 128 unl rows (zero-fill past 2500); stride 66 -> float2 writes
    for (int i = tid; i < 128 * 16; i += 256) {
        int row = i >> 4, c4 = (i & 15) * 4;
        int m = m0 + row;
        float4 x = make_float4(0.f, 0.f, 0.f, 0.f);
        if (m < 2500) x = *(const float4*)(unl_n + ((size_t)(b * 2500 + m)) * 64 + c4);
        *(float2*)&uls[row * 66 + c4]     = make_float2(x.x, x.y);
        *(float2*)&uls[row * 66 + c4 + 2] = make_float2(x.z, x.w);
    }
    __syncthreads();

    int ml = tid & 127;              // local m
    int m  = m0 + ml;
    int nh = tid >> 7;               // n-half: 0 or 1 (constant within a wave)
    int nbase = nh * 16;
    int nbu = __builtin_amdgcn_readfirstlane(nbase);
    int nn_total = (125 - n0) < 32 ? (125 - n0) : 32;   // 32,32,32,29
    const float* sbp = supT + ((size_t)bw * 64) * 128 + n0 + nbu;  // wave-uniform

    float acc[16];
#pragma unroll
    for (int j = 0; j < 16; ++j) acc[j] = 0.f;

    KB8(0)  KB8(8)  KB8(16) KB8(24)
    KB8(32) KB8(40) KB8(48) KB8(56)

    // row-side running argmax over this thread's 16 n's (ascending, strict >)
    int nnloc = nn_total - nbase;
    nnloc = nnloc < 0 ? 0 : (nnloc > 16 ? 16 : nnloc);
    float rbv = NEGINF; int rbi = 0;
    for (int j = 0; j < nnloc; ++j)
        if (acc[j] > rbv) { rbv = acc[j]; rbi = n0 + nbase + j; }
    if (m < 2500) {
        int ck = nc * 2 + nh;        // chunk 0..7, ascending global n
        rowv[((size_t)bw * 8 + ck) * 2500 + m] = rbv;
        rowi[((size_t)bw * 8 + ck) * 2500 + m] = rbi;
    }

    // col-side: wave max + ballot/ffs min-m tie-break
#pragma unroll
    for (int j = 0; j < 16; ++j) {
        float v = (m < 2500 && (nbase + j) < nn_total) ? acc[j] : NEGINF;
        float vm = v;
#pragma unroll
        for (int s2 = 1; s2 < 64; s2 <<= 1) vm = fmaxf(vm, __shfl_xor(vm, s2));
        unsigned long long msk = __ballot(v == vm);
        int first = __ffsll((unsigned long long)msk) - 1;
        if (lane == 0) { sv_[wv][nbase + j] = vm; si_[wv][nbase + j] = m0 + (wv & 1) * 64 + first; }
    }
    __syncthreads();
    if (tid < nn_total) {
        int w0 = (tid < 16) ? 0 : 2;
        float v = sv_[w0][tid];     int vi = si_[w0][tid];
        float v2 = sv_[w0 + 1][tid]; int i2 = si_[w0 + 1][tid];
        if (v2 > v || (v2 == v && i2 < vi)) { v = v2; vi = i2; }
        float* cv = colvi + ((((size_t)bw) * 125 + (n0 + tid)) * 20 + mb) * 2;
        cv[0] = v; ((int*)cv)[1] = vi;
    }
}

// ============================================================
// Kernel M: merge partials. 196 blocks x 64. (verbatim round-5)
// ============================================================
__global__ __launch_bounds__(64) void kmerge(
    const float* __restrict__ rowv, const int* __restrict__ rowi,
    const float* __restrict__ colvi,
    int* __restrict__ unear, int* __restrict__ snear)
{
    int it = blockIdx.x * 64 + threadIdx.x;
    if (it < 10000) {
        int b = it / 2500, m = it % 2500;
        float bv = NEGINF; int bi = 0;
#pragma unroll
        for (int w = 0; w < 5; ++w) {
#pragma unroll
            for (int ck = 0; ck < 8; ++ck) {
                size_t o = (((size_t)(b * 5 + w)) * 8 + ck) * 2500 + m;
                float v = rowv[o];
                if (v > bv) { bv = v; bi = w * 125 + rowi[o]; }
            }
        }
        unear[it] = bi;
    } else if (it < 12500) {
        int idx = it - 10000;
        const float* p = colvi + (size_t)idx * 40;
        float bv = NEGINF; int bi = 0x7fffffff;
        for (int mb2 = 0; mb2 < 20; ++mb2) {
            float v = p[mb2 * 2]; int vi = ((const int*)p)[mb2 * 2 + 1];
            if (v > bv || (v == bv && vi < bi)) { bv = v; bi = vi; }
        }
        snear[idx] = bi;
    }
}

// ============================================================
// Kernel P: mutual-NN mask + stable stream compaction. 20 blocks x 256.
// (verbatim round-5)
// ============================================================
__global__ __launch_bounds__(256) void kcmp(
    const int* __restrict__ unear, const int* __restrict__ snear,
    int* __restrict__ cmp, int* __restrict__ cntg)
{
    int p = blockIdx.x;
    int b = p / 5, way = p % 5;
    int tid = threadIdx.x, lane = tid & 63, wv = tid >> 6;
    __shared__ unsigned long long masks[40];
    __shared__ int base[40];

    for (int ch = wv; ch < 40; ch += 4) {
        int m = ch * 64 + lane;
        bool ok = false;
        if (m < 2500) {
            int un = unear[b * 2500 + m];
            ok = (un / 125 == way) && (snear[b * 625 + un] == m);
        }
        unsigned long long msk = __ballot(ok ? 1 : 0);
        if (lane == 0) masks[ch] = msk;
    }
    __syncthreads();
    if (tid == 0) {
        int s = 0;
        for (int ch = 0; ch < 40; ++ch) { base[ch] = s; s += __popcll(masks[ch]); }
        cntg[p] = s;
    }
    __syncthreads();
    for (int ch = wv; ch < 40; ch += 4) {
        unsigned long long msk = masks[ch];
        if ((msk >> lane) & 1ull) {
            int pre = __popcll(msk & ((1ull << lane) - 1ull));
            cmp[(size_t)p * 2500 + base[ch] + pre] = ch * 64 + lane;
        }
    }
}

// ============================================================
// Kernel C1: verbatim round-5 (bench-proven, 44.4us). Q on scalar
// pipe via s_load_dwordx4 (28 SGPRs pinned), batch loop, wave-local
// row-argmax + 4-wave column combine. The r6 batch-split regressed
// (71us: per-block prologue overhead x4, VALUBusy 73%) - reverted.
// ============================================================
#define QLOAD(CG, Q0,Q1,Q2,Q3,Q4,Q5,Q6) \
  asm volatile( \
    "s_load_dwordx4 %0, %[b], %c[o0]\n\t" \
    "s_load_dwordx4 %1, %[b], %c[o1]\n\t" \
    "s_load_dwordx4 %2, %[b], %c[o2]\n\t" \
    "s_load_dwordx4 %3, %[b], %c[o3]\n\t" \
    "s_load_dwordx4 %4, %[b], %c[o4]\n\t" \
    "s_load_dwordx4 %5, %[b], %c[o5]\n\t" \
    "s_load_dwordx4 %6, %[b], %c[o6]\n\t" \
    "s_waitcnt lgkmcnt(0)" \
    : "=s"(Q0), "=s"(Q1), "=s"(Q2), "=s"(Q3), "=s"(Q4), "=s"(Q5), "=s"(Q6) \
    : [b]"s"(qbp), \
      [o0]"i"((CG)*16 + 0*256), [o1]"i"((CG)*16 + 1*256), \
      [o2]"i"((CG)*16 + 2*256), [o3]"i"((CG)*16 + 3*256), \
      [o4]"i"((CG)*16 + 4*256), [o5]"i"((CG)*16 + 5*256), \
      [o6]"i"((CG)*16 + 6*256))

#define CGSTEP(CG) { \
    f4s q0,q1,q2,q3,q4,q5,q6; \
    QLOAD(CG, q0,q1,q2,q3,q4,q5,q6); \
    float4 cl = *(const float4*)&cls[lane * 68 + (CG) * 4]; \
    acc[0]=fmaf(q0.x,cl.x,fmaf(q0.y,cl.y,fmaf(q0.z,cl.z,fmaf(q0.w,cl.w,acc[0])))); \
    acc[1]=fmaf(q1.x,cl.x,fmaf(q1.y,cl.y,fmaf(q1.z,cl.z,fmaf(q1.w,cl.w,acc[1])))); \
    acc[2]=fmaf(q2.x,cl.x,fmaf(q2.y,cl.y,fmaf(q2.z,cl.z,fmaf(q2.w,cl.w,acc[2])))); \
    acc[3]=fmaf(q3.x,cl.x,fmaf(q3.y,cl.y,fmaf(q3.z,cl.z,fmaf(q3.w,cl.w,acc[3])))); \
    acc[4]=fmaf(q4.x,cl.x,fmaf(q4.y,cl.y,fmaf(q4.z,cl.z,fmaf(q4.w,cl.w,acc[4])))); \
    acc[5]=fmaf(q5.x,cl.x,fmaf(q5.y,cl.y,fmaf(q5.z,cl.z,fmaf(q5.w,cl.w,acc[5])))); \
    acc[6]=fmaf(q6.x,cl.x,fmaf(q6.y,cl.y,fmaf(q6.z,cl.z,fmaf(q6.w,cl.w,acc[6])))); }

__global__ __launch_bounds__(256) void kc1(
    const float* __restrict__ qt, const float* __restrict__ sup_n,
    const float* __restrict__ unl_n, const int* __restrict__ cmp,
    const int* __restrict__ cntg,
    float* __restrict__ bvg, int* __restrict__ bpg,
    unsigned char* __restrict__ amaxg)
{
    int bid = blockIdx.x;
    int w = bid % 5, bq = bid / 5;
    int b = bq / 75;
    int tid = threadIdx.x;
    int lane = tid & 63;
    int wvu = __builtin_amdgcn_readfirstlane(tid >> 6);   // wave id, SGPR
    int pbw = b * 5 + w;

    int L = 0;
#pragma unroll
    for (int i = 0; i < 20; ++i) { int v = cntg[i]; L = L > v ? L : v; }
    int cntw = 0, wb = 0;
#pragma unroll
    for (int w2 = 0; w2 < 5; ++w2) {
        int c2 = cntg[b * 5 + w2];
        if (w2 < w) wb += 125 + c2;
        if (w2 == w) cntw = c2;
    }
    int cw = 125 + cntw;             // 125..250

    __shared__ float cls[64 * 68];   // 64 cols x 64c, stride 68 (16B-aligned rows)
    __shared__ float amxv[4][64];
    __shared__ int   amxg_[4][64];
    __shared__ float redv[25];
    __shared__ int   redn[25];

    // wave-uniform Q base: qT + bq*28*64 + (wvu*7)*64
    const float* qbp = qt + ((size_t)bq * 28 + wvu * 7) * 64;

    float rv[7]; int rn[7];
#pragma unroll
    for (int j = 0; j < 7; ++j) { rv[j] = NEGINF; rn[j] = 0x7fffffff; }

    int nb = (cw + 63) >> 6;         // 2..4 batches of 64 cols

    for (int b4 = 0; b4 < nb; ++b4) {
        // column-argmax combine for previous batch (reads amx; disjoint from cls)
        if (b4 > 0 && tid < 64) {
            int n = (b4 - 1) * 64 + tid;
            if (n < cw) {
                float v = amxv[0][tid]; int g = amxg_[0][tid];
#pragma unroll
                for (int g2 = 1; g2 < 4; ++g2)
                    if (amxv[g2][tid] > v) { v = amxv[g2][tid]; g = amxg_[g2][tid]; }
                amaxg[(size_t)bq * 3200 + (wb + n)] = (unsigned char)g;
            }
        }
        // stage 64 cols (zero past cw): coalesced 16-lane rows
#pragma unroll
        for (int k = 0; k < 4; ++k) {
            int i = tid + k * 256;
            int row = i >> 4, ch = i & 15;
            int n = b4 * 64 + row;
            float4 x = make_float4(0.f, 0.f, 0.f, 0.f);
            if (n < cw) {
                const float* cp;
                if (n < 125) cp = sup_n + (((size_t)pbw) * 125 + n) * 64;
                else { int m = cmp[((size_t)pbw) * 2500 + (n - 125)];
                       cp = unl_n + ((size_t)(b * 2500 + m)) * 64; }
                x = *(const float4*)(cp + ch * 4);
            }
            *(float4*)&cls[row * 68 + ch * 4] = x;
        }
        __syncthreads();

        float acc[7];
#pragma unroll
        for (int j = 0; j < 7; ++j) acc[j] = 0.f;

        CGSTEP(0);  CGSTEP(1);  CGSTEP(2);  CGSTEP(3);
        CGSTEP(4);  CGSTEP(5);  CGSTEP(6);  CGSTEP(7);
        CGSTEP(8);  CGSTEP(9);  CGSTEP(10); CGSTEP(11);
        CGSTEP(12); CGSTEP(13); CGSTEP(14); CGSTEP(15);

        bool colvalid = (b4 * 64 + lane) < cw;
        float cmax = NEGINF; int cam = 0;
#pragma unroll
        for (int j = 0; j < 7; ++j) {
            int mq = wvu * 7 + j;
            float s = (acc[j] + 1.0f) * 0.5f;
            float sm = (colvalid && mq < 25) ? s : NEGINF;
            if (sm > cmax) { cmax = sm; cam = mq; }      // col-argmax partial (min mq)
            float vm = sm;                                // row-argmax over 64 cols
#pragma unroll
            for (int t = 1; t < 64; t <<= 1) vm = fmaxf(vm, __shfl_xor(vm, t));
            unsigned long long msk = __ballot(sm == vm);
            int first = __ffsll(msk) - 1;                 // min lane == min col
            if (vm > rv[j]) { rv[j] = vm; rn[j] = b4 * 64 + first; }
        }
        amxv[wvu][lane] = cmax; amxg_[wvu][lane] = cam;
        __syncthreads();
    }

    // final batch's column-argmax combine
    if (tid < 64) {
        int n = (nb - 1) * 64 + tid;
        if (n < cw) {
            float v = amxv[0][tid]; int g = amxg_[0][tid];
#pragma unroll
            for (int g2 = 1; g2 < 4; ++g2)
                if (amxv[g2][tid] > v) { v = amxv[g2][tid]; g = amxg_[g2][tid]; }
            amaxg[(size_t)bq * 3200 + (wb + n)] = (unsigned char)g;
        }
    }
    if (lane == 0) {
#pragma unroll
        for (int j = 0; j < 7; ++j) {
            int mq = wvu * 7 + j;
            if (mq < 25) { redv[mq] = rv[j]; redn[mq] = rn[j]; }
        }
    }
    __syncthreads();

    if (tid < 25) {
        float v = redv[tid]; int nn = redn[tid];
        int p = ((w * 2625 + nn) << 12) | (wb + nn);
        if (L > cntw) {              // ghost pad column (value 0.5) past this way's count
            int pp = ((w * 2625 + 125 + cntw) << 12) | 0xFFF;
            if (0.5f > v || (0.5f == v && pp < p)) { v = 0.5f; p = pp; }
        }
        size_t o = ((size_t)bq * 5 + w) * 25 + tid;
        bvg[o] = v; bpg[o] = p;
    }
}

// ============================================================
// Kernel CE: merge 5 way-partials per (bq,mq), mutual mask, row loss,
// atomicAdd into d_out. 300 blocks x 64. (verbatim round-5)
// ============================================================
__global__ __launch_bounds__(64) void kce(
    const float* __restrict__ bvg, const int* __restrict__ bpg,
    const unsigned char* __restrict__ amaxg, const int* __restrict__ qy,
    float* __restrict__ out)
{
    int bq = blockIdx.x;
    int tid = threadIdx.x;
    __shared__ float qmask[25];
    __shared__ float lg[5];
    if (tid < 25) {
        float v = NEGINF; int p = 0x7fffffff;
#pragma unroll
        for (int w = 0; w < 5; ++w) {
            size_t o = ((size_t)bq * 5 + w) * 25 + tid;
            float v2 = bvg[o]; int p2 = bpg[o];
            if (v2 > v || (v2 == v && p2 < p)) { v = v2; p = p2; }
        }
        int pos = p & 0xFFF;
        int g = (pos == 0xFFF) ? 0 : (int)amaxg[(size_t)bq * 3200 + pos];
        qmask[tid] = (g == tid) ? 1.0f : 0.0f;
    }
    __syncthreads();
    if (tid < 5) {
        float s = 0.f;
#pragma unroll
        for (int mq = 0; mq < 25; ++mq)
            s += bvg[((size_t)bq * 5 + tid) * 25 + mq] * qmask[mq];
        lg[tid] = s;
    }
    __syncthreads();
    if (tid == 0) {
        int y = qy[bq];
        float mx = lg[0];
#pragma unroll
        for (int w = 1; w < 5; ++w) mx = fmaxf(mx, lg[w]);
        float se = 0.f;
#pragma unroll
        for (int w = 0; w < 5; ++w) se += expf(lg[w] - mx);
        float loss = -(lg[y] - mx - logf(se));
        atomicAdd(out, loss * (1.0f / 300.0f));
    }
}

// ============================================================
extern "C" void kernel_launch(void* const* d_in, const int* in_sizes, int n_in,
                              void* d_out, int out_size, void* d_ws, size_t ws_size,
                              hipStream_t stream)
{
    const float* sup = (const float*)d_in[0];
    const float* qry = (const float*)d_in[2];
    const int*   qy  = (const int*)d_in[3];
    const float* unl = (const float*)d_in[4];

    float* ws    = (float*)d_ws;
    float* unl_n = ws + OF_UNL;
    float* sup_n = ws + OF_SUP;
    float* supT  = ws + OF_SUPT;
    float* qt    = ws + OF_QT;
    float* rowv  = ws + OF_ROWV;
    int*   rowi  = (int*)(ws + OF_ROWI);
    float* colvi = ws + OF_CVI;
    int*   cmp   = (int*)(ws + OF_CMP);
    int*   cntg  = (int*)(ws + OF_CNT);
    int*   unear = (int*)(ws + OF_UNEAR);
    int*   snear = (int*)(ws + OF_SNEAR);
    float* bvg   = ws + OF_BV;
    int*   bpg   = (int*)(ws + OF_BP);
    unsigned char* amaxg = (unsigned char*)(ws + OF_AMX);

    hipMemsetAsync(d_out, 0, sizeof(float), stream);

    hipLaunchKernelGGL(knorm, dim3(200), dim3(256), 0, stream,
                       sup, qry, unl, unl_n, sup_n, supT, qt);
    hipLaunchKernelGGL(kb, dim3(1600), dim3(256), 0, stream,
                       unl_n, supT, rowv, rowi, colvi);
    hipLaunchKernelGGL(kmerge, dim3(196), dim3(64), 0, stream,
                       rowv, rowi, colvi, unear, snear);
    hipLaunchKernelGGL(kcmp, dim3(20), dim3(256), 0, stream,
                       unear, snear, cmp, cntg);
    hipLaunchKernelGGL(kc1, dim3(1500), dim3(256), 0, stream,
                       qt, sup_n, unl_n, cmp, cntg, bvg, bpg, amaxg);
    hipLaunchKernelGGL(kce, dim3(300), dim3(64), 0, stream,
                       bvg, bpg, amaxg, qy, (float*)d_out);
}